// Round 7
// baseline (885.082 us; speedup 1.0000x reference)
//
#include <hip/hip_runtime.h>
#include <cstdint>
#include <cstddef>

#define N_NODES   100000
#define M_PAD     100096   // 782 * 128
#define DIM       256
#define NTYPES    6
#define M_EDGES   400000
#define TOTAL_E   2400000
#define HALF_E    1200000
#define QUART_E   600000
#define NCNT      200000   // 2 halves * N_NODES
#define NCOPY     8
#define NSCAN     1600000  // NCOPY * NCNT, copy-major: lin = c*NCNT + slot
#define SCAN_BLKS 1563     // ceil(NSCAN/1024)

typedef _Float16 f16x8 __attribute__((ext_vector_type(8)));
typedef _Float16 f16x4 __attribute__((ext_vector_type(4)));
typedef float    f32x4 __attribute__((ext_vector_type(4)));

// ---- A16 = fp16(X), rows padded to M_PAD ----------------------------------
__global__ void build_a16(const float* __restrict__ x, _Float16* __restrict__ Ap){
    int tid = blockIdx.x * 256 + threadIdx.x;   // M_PAD*256/8 threads exact
    int idx = tid << 3;
    int row = idx >> 8;
    int k   = idx & 255;
    f16x8 h;
    if (row < N_NODES){
        const f32x4* px = (const f32x4*)(x + (size_t)row * DIM + k);
        f32x4 v0 = __builtin_nontemporal_load(px);
        f32x4 v1 = __builtin_nontemporal_load(px + 1);
        h[0] = (_Float16)v0[0]; h[1] = (_Float16)v0[1]; h[2] = (_Float16)v0[2]; h[3] = (_Float16)v0[3];
        h[4] = (_Float16)v1[0]; h[5] = (_Float16)v1[1]; h[6] = (_Float16)v1[2]; h[7] = (_Float16)v1[3];
    } else {
        #pragma unroll
        for (int j = 0; j < 8; ++j) h[j] = (_Float16)0.f;
    }
    *(f16x8*)(Ap + (size_t)row * 256 + k) = h;
}

// ---- B16 = fp16(W)  (1536 x 256) ------------------------------------------
__global__ void build_b16(const float* __restrict__ W, _Float16* __restrict__ Bp){
    int tid = blockIdx.x * 256 + threadIdx.x;   // 1536*256/8 threads exact
    int idx = tid << 3;
    const f32x4* pw = (const f32x4*)(W + idx);
    f32x4 v0 = __builtin_nontemporal_load(pw);
    f32x4 v1 = __builtin_nontemporal_load(pw + 1);
    f16x8 h;
    h[0] = (_Float16)v0[0]; h[1] = (_Float16)v0[1]; h[2] = (_Float16)v0[2]; h[3] = (_Float16)v0[3];
    h[4] = (_Float16)v1[0]; h[5] = (_Float16)v1[1]; h[6] = (_Float16)v1[2]; h[7] = (_Float16)v1[3];
    *(f16x8*)(Bp + idx) = h;
}

// ---- gating table 2*sigmoid(posemb @ Wp^T + bp), fp64 trig, fp16 out ------
__global__ void build_gating(const float* __restrict__ Wp, const float* __restrict__ bp,
                             _Float16* __restrict__ gate){
    __shared__ float semb[256];
    int p = blockIdx.x;     // 0..511
    int t = threadIdx.x;    // 0..255
    if (t < 127){
        double invf = exp(-log(10000.0) * (2.0 * t) / 254.0);
        double a = (double)p * invf;
        semb[t]       = (float)sin(a);
        semb[t + 127] = (float)cos(a);
    } else if (t >= 254){
        semb[t] = 0.0f;
    }
    __syncthreads();
    float z = bp[t];
    const float* wr = Wp + (size_t)t * 256;
    #pragma unroll 4
    for (int kq = 0; kq < 256; ++kq) z += semb[kq] * wr[kq];
    gate[(size_t)p * 256 + t] = (_Float16)(2.0f / (1.0f + expf(-z)));
}

// ---- CSR over (half,tgt), copy-major: each XCD owns a private contiguous --
// region of packed[]  (cnt/cursor/off_lin all at lin = copy*NCNT + slot)
__global__ void hist_kernel(const int* __restrict__ edges, int* __restrict__ cnt){
    int t0 = blockIdx.x * 256 + threadIdx.x;
    if (t0 >= QUART_E) return;
    int copy = blockIdx.x & 7;
    #pragma unroll
    for (int j = 0; j < 4; ++j){
        int e = t0 + j * QUART_E;
        int half = e / HALF_E;
        int tgt = edges[(size_t)e * 2 + 1];
        atomicAdd(cnt + copy * NCNT + half * N_NODES + tgt, 1);
    }
}

__global__ void scan1_kernel(const int* __restrict__ cnt, int* __restrict__ off_lin,
                             int* __restrict__ bsum){
    __shared__ int lds[256];
    int t = threadIdx.x;
    int base = blockIdx.x * 1024 + t * 4;
    int v[4]; int s = 0;
    #pragma unroll
    for (int j = 0; j < 4; ++j){
        int i = base + j;
        int val = (i < NSCAN) ? cnt[i] : 0;
        v[j] = val; s += val;
    }
    lds[t] = s; __syncthreads();
    for (int d = 1; d < 256; d <<= 1){
        int xv = (t >= d) ? lds[t - d] : 0;
        __syncthreads();
        lds[t] += xv;
        __syncthreads();
    }
    int run = (t > 0) ? lds[t - 1] : 0;
    #pragma unroll
    for (int j = 0; j < 4; ++j){ int i = base + j; if (i < NSCAN) off_lin[i] = run; run += v[j]; }
    if (t == 255) bsum[blockIdx.x] = run;
}

__global__ void scan2_kernel(const int* __restrict__ bsum, int* __restrict__ ssum){
    __shared__ int lds[256];
    __shared__ int carry;
    int t = threadIdx.x;
    if (t == 0) carry = 0;
    __syncthreads();
    for (int ch = 0; ch < 7; ++ch){
        int idx = ch * 256 + t;
        int v = (idx < SCAN_BLKS) ? bsum[idx] : 0;
        lds[t] = v; __syncthreads();
        for (int d = 1; d < 256; d <<= 1){
            int xv = (t >= d) ? lds[t - d] : 0;
            __syncthreads();
            lds[t] += xv;
            __syncthreads();
        }
        int ex = carry + ((t > 0) ? lds[t - 1] : 0);
        if (idx < SCAN_BLKS) ssum[idx] = ex;
        __syncthreads();
        if (t == 255) carry += lds[255];
        __syncthreads();
    }
}

__global__ void scan3_kernel(int* __restrict__ off_lin, const int* __restrict__ ssum,
                             int* __restrict__ cursor){
    int i = blockIdx.x * 256 + threadIdx.x;   // NSCAN exact
    int vv = off_lin[i] + ssum[i >> 10];
    off_lin[i] = vv;
    cursor[i] = vv;
    if (i == 0) off_lin[NSCAN] = TOTAL_E;     // sentinel
}

__global__ void scatter_kernel(const int* __restrict__ edges, const int* __restrict__ posl,
                               int* __restrict__ cursor, unsigned* __restrict__ packed){
    int t0 = blockIdx.x * 256 + threadIdx.x;
    if (t0 >= QUART_E) return;
    int copy = blockIdx.x & 7;
    #pragma unroll
    for (int j = 0; j < 4; ++j){
        int e = t0 + j * QUART_E;
        int type = e / M_EDGES;
        int half = e / HALF_E;
        int typ3 = type - half * 3;
        int2 ed = *(const int2*)(edges + (size_t)e * 2);
        int p = atomicAdd(cursor + copy * NCNT + half * N_NODES + ed.y, 1);
        packed[p] = (unsigned)ed.x | ((unsigned)posl[e] << 17) | ((unsigned)typ3 << 26);
    }
}

// ---- fp16 NT GEMM trio: prop_t = A16 * B_t^T + b_t for 3 types ------------
// coalesced epilogue: per-wave LDS staging, f16x8 full-line stores
__global__ __launch_bounds__(512, 4) void gemm_f16(
        const _Float16* __restrict__ Ap,
        const _Float16* __restrict__ Bbase,
        const float* __restrict__ bbase,
        _Float16* __restrict__ prop)
{
    __shared__ __align__(16) char smem[49152];
    _Float16* sA = (_Float16*)smem;                 // 128*64 fp16 = 16 KB
    _Float16* sB = (_Float16*)(smem + 16384);       // 256*64 fp16 = 32 KB
    const int bid  = blockIdx.x;
    const int rp   = bid / 3;
    const int t    = bid - rp * 3;
    const int tid  = threadIdx.x;
    const int lane = tid & 63;
    const int wid  = tid >> 6;
    const int wr   = wid >> 2;   // 0..1
    const int wc   = wid & 3;    // 0..3
    const size_t m0 = (size_t)rp * 128;
    const _Float16* Bt = Bbase + (size_t)t * 256 * 256;

    f32x4 acc[4][4];
    #pragma unroll
    for (int m = 0; m < 4; ++m)
        #pragma unroll
        for (int n = 0; n < 4; ++n)
            acc[m][n] = (f32x4){0.f, 0.f, 0.f, 0.f};

    const int sub = lane >> 3;        // row within 8-row chunk
    const int bib = (lane & 7) << 4;  // byte within 128B row

    for (int kk = 0; kk < 4; ++kk){
        #pragma unroll
        for (int ci = 0; ci < 6; ++ci){
            int c = wid * 6 + ci;
            const _Float16* grow;
            _Float16* lrow;
            int r;
            if (c < 16){
                r = (c << 3) + sub;                     // 0..127
                grow = Ap + (m0 + (size_t)r) * 256;
                lrow = sA + r * 64;
            } else {
                r = ((c - 16) << 3) + sub;              // 0..255
                grow = Bt + (size_t)r * 256;
                lrow = sB + r * 64;
            }
            uint4 v = *(const uint4*)((const char*)grow + (kk << 7) + bib);
            int sw = bib ^ ((r & 7) << 4);
            *(uint4*)((char*)lrow + sw) = v;
        }
        __syncthreads();

        #pragma unroll
        for (int ks = 0; ks < 2; ++ks){
            int slot = (ks << 6) + ((lane >> 4) << 4);
            f16x8 af[4];
            #pragma unroll
            for (int m = 0; m < 4; ++m){
                int rA = (wr << 6) + (m << 4) + (lane & 15);
                af[m] = *(const f16x8*)((const char*)sA + rA * 128 + (slot ^ ((rA & 7) << 4)));
            }
            #pragma unroll
            for (int n = 0; n < 4; ++n){
                int rB = (wc << 6) + (n << 4) + (lane & 15);
                f16x8 bfr = *(const f16x8*)((const char*)sB + rB * 128 + (slot ^ ((rB & 7) << 4)));
                #pragma unroll
                for (int m = 0; m < 4; ++m)
                    acc[m][n] = __builtin_amdgcn_mfma_f32_16x16x32_f16(af[m], bfr, acc[m][n], 0, 0, 0);
            }
        }
        __syncthreads();
    }

    // ---- coalesced epilogue: stage 32-row half-tiles in private LDS slice --
    char* stage = smem + wid * 4096;
    _Float16* Ct = prop + (size_t)t * M_PAD * 256;
    float bv[4];
    #pragma unroll
    for (int n = 0; n < 4; ++n)
        bv[n] = bbase[(size_t)t * 256 + (wc << 6) + (n << 4) + (lane & 15)];

    #pragma unroll
    for (int ph = 0; ph < 2; ++ph){
        #pragma unroll
        for (int m2 = 0; m2 < 2; ++m2){
            int m = (ph << 1) + m2;
            #pragma unroll
            for (int n = 0; n < 4; ++n){
                #pragma unroll
                for (int j = 0; j < 4; ++j){
                    int lrow  = (m2 << 4) + ((lane >> 4) << 2) + j;
                    int lcolb = ((((n << 4) + (lane & 15)) << 1)) ^ (((lrow >> 2) & 3) << 5);
                    *(_Float16*)(stage + lrow * 128 + lcolb) =
                        (_Float16)(acc[m][n][j] + bv[n]);
                }
            }
        }
        #pragma unroll
        for (int r8 = 0; r8 < 4; ++r8){
            int lrow  = (r8 << 3) + (lane >> 3);
            int lcolb = (((lane & 7) << 4)) ^ (((lrow >> 2) & 3) << 5);
            f16x8 v = *(const f16x8*)(stage + lrow * 128 + lcolb);
            int grow = (int)m0 + (wr << 6) + (ph << 5) + lrow;
            int gcol = (wc << 6) + ((lane & 7) << 3);
            *(f16x8*)(Ct + (size_t)grow * 256 + gcol) = v;
        }
    }
}

// ---- half aggregation: 3 L3-resident props, one wave per target ------------
// nt out traffic (keep L3 for prop gather); ILP-4; v_pk_mul_f16 + f32 accum.
__global__ void aggregate(const _Float16* __restrict__ prop, const _Float16* __restrict__ gate,
                          const unsigned* __restrict__ packed,
                          const int* __restrict__ off_lin,
                          int h, float* __restrict__ out)
{
    int tgt  = blockIdx.x * 4 + (threadIdx.x >> 6);
    int lane = threadIdx.x & 63;
    int s    = h * N_NODES + tgt;

    int st[8], P[9];
    P[0] = 0;
    #pragma unroll
    for (int c = 0; c < 8; ++c){
        int a0 = off_lin[c * NCNT + s];
        int a1 = off_lin[c * NCNT + s + 1];
        st[c] = a0;
        P[c + 1] = P[c] + (a1 - a0);
    }
    int n = P[8];

    f32x4 acc0 = (f32x4){0.f,0.f,0.f,0.f};
    f32x4 acc1 = (f32x4){0.f,0.f,0.f,0.f};
    f32x4 acc2 = (f32x4){0.f,0.f,0.f,0.f};
    f32x4 acc3 = (f32x4){0.f,0.f,0.f,0.f};

    for (int c0 = 0; c0 < n; c0 += 64){
        int e = c0 + lane;
        int idx = st[0] + e;
        #pragma unroll
        for (int c = 1; c < 8; ++c)
            if (e >= P[c]) idx = st[c] + (e - P[c]);
        unsigned wv = (e < n) ? __builtin_nontemporal_load(packed + idx) : 0u;
        int m = n - c0; if (m > 64) m = 64;
        int e2 = 0;
        for (; e2 + 3 < m; e2 += 4){
            unsigned w[4];
            #pragma unroll
            for (int j = 0; j < 4; ++j)
                w[j] = (unsigned)__builtin_amdgcn_readlane((int)wv, e2 + j);
            f16x4 pm[4];
            #pragma unroll
            for (int j = 0; j < 4; ++j){
                int src = (int)(w[j] & 0x1FFFFu);
                int pz  = (int)((w[j] >> 17) & 0x1FFu);
                int ty  = (int)(w[j] >> 26);
                f16x4 pv = *(const f16x4*)(prop + ((size_t)ty * M_PAD + (size_t)src) * 256 + lane * 4);
                f16x4 gv = *(const f16x4*)(gate + (size_t)pz * 256 + lane * 4);
                pm[j] = pv * gv;     // v_pk_mul_f16
            }
            acc0[0] += (float)pm[0][0]; acc0[1] += (float)pm[0][1];
            acc0[2] += (float)pm[0][2]; acc0[3] += (float)pm[0][3];
            acc1[0] += (float)pm[1][0]; acc1[1] += (float)pm[1][1];
            acc1[2] += (float)pm[1][2]; acc1[3] += (float)pm[1][3];
            acc2[0] += (float)pm[2][0]; acc2[1] += (float)pm[2][1];
            acc2[2] += (float)pm[2][2]; acc2[3] += (float)pm[2][3];
            acc3[0] += (float)pm[3][0]; acc3[1] += (float)pm[3][1];
            acc3[2] += (float)pm[3][2]; acc3[3] += (float)pm[3][3];
        }
        for (; e2 < m; ++e2){
            unsigned w0 = (unsigned)__builtin_amdgcn_readlane((int)wv, e2);
            int src = (int)(w0 & 0x1FFFFu);
            int pz  = (int)((w0 >> 17) & 0x1FFu);
            int ty  = (int)(w0 >> 26);
            f16x4 pv = *(const f16x4*)(prop + ((size_t)ty * M_PAD + (size_t)src) * 256 + lane * 4);
            f16x4 gv = *(const f16x4*)(gate + (size_t)pz * 256 + lane * 4);
            f16x4 pm = pv * gv;
            acc0[0] += (float)pm[0]; acc0[1] += (float)pm[1];
            acc0[2] += (float)pm[2]; acc0[3] += (float)pm[3];
        }
    }
    acc0 += acc1; acc2 += acc3; acc0 += acc2;

    f32x4* op = (f32x4*)(out + (size_t)tgt * DIM) + lane;
    if (h == 0){
        __builtin_nontemporal_store(acc0, op);
    } else {
        int deg = n;
        #pragma unroll
        for (int c = 0; c < 8; ++c)
            deg += off_lin[c * NCNT + tgt + 1] - off_lin[c * NCNT + tgt];
        float inv = ((deg == 0) ? 1.0f : (float)deg) + 1e-8f;
        f32x4 cur = __builtin_nontemporal_load(op);
        cur += acc0;
        cur[0] /= inv; cur[1] /= inv; cur[2] /= inv; cur[3] /= inv;
        __builtin_nontemporal_store(cur, op);
    }
}

extern "C" void kernel_launch(void* const* d_in, const int* in_sizes, int n_in,
                              void* d_out, int out_size, void* d_ws, size_t ws_size,
                              hipStream_t stream)
{
    const float* x     = (const float*)d_in[0];
    const float* W     = (const float*)d_in[1];
    const float* b     = (const float*)d_in[2];
    const float* Wp    = (const float*)d_in[3];
    const float* bp    = (const float*)d_in[4];
    const int*   edges = (const int*)d_in[5];
    const int*   posl  = (const int*)d_in[6];
    float* out = (float*)d_out;

    char* ws = (char*)d_ws;
    size_t o = 0;
    auto alloc = [&](size_t bytes){ void* p = ws + o; o += (bytes + 255) & ~(size_t)255; return p; };

    _Float16* Ap   = (_Float16*)alloc((size_t)M_PAD * 256 * 2);
    _Float16* prop = (_Float16*)alloc((size_t)3 * M_PAD * 256 * 2);
    _Float16* Bp   = (_Float16*)alloc((size_t)NTYPES * 256 * 256 * 2);
    _Float16* gate = (_Float16*)alloc((size_t)512 * 256 * 2);
    int* cnt     = (int*)alloc((size_t)NSCAN * 4);
    int* off_lin = (int*)alloc((size_t)(NSCAN + 8) * 4);
    int* cursor  = (int*)alloc((size_t)NSCAN * 4);
    unsigned* packed = (unsigned*)alloc((size_t)TOTAL_E * 4);
    int* bsum   = (int*)alloc((size_t)SCAN_BLKS * 4 + 256);
    int* ssum   = (int*)alloc((size_t)SCAN_BLKS * 4 + 256);

    hipMemsetAsync(cnt, 0, (size_t)NSCAN * 4, stream);

    build_a16<<<12512, 256, 0, stream>>>(x, Ap);
    build_b16<<<192, 256, 0, stream>>>(W, Bp);
    build_gating<<<512, 256, 0, stream>>>(Wp, bp, gate);
    hist_kernel<<<2344, 256, 0, stream>>>(edges, cnt);
    scan1_kernel<<<SCAN_BLKS, 256, 0, stream>>>(cnt, off_lin, bsum);
    scan2_kernel<<<1, 256, 0, stream>>>(bsum, ssum);
    scan3_kernel<<<6250, 256, 0, stream>>>(off_lin, ssum, cursor);
    scatter_kernel<<<2344, 256, 0, stream>>>(edges, posl, cursor, packed);

    for (int h = 0; h < 2; ++h){
        gemm_f16<<<2346, 512, 0, stream>>>(Ap, Bp + (size_t)h * 3 * 256 * 256,
                                           b + (size_t)h * 3 * 256, prop);
        aggregate<<<25000, 256, 0, stream>>>(prop, gate, packed, off_lin, h, out);
    }
}

// Round 8
// 824.482 us; speedup vs baseline: 1.0735x; 1.0735x over previous
//
#include <hip/hip_runtime.h>
#include <cstdint>
#include <cstddef>

#define N_NODES   100000
#define M_PAD     100096   // 782 * 128
#define DIM       256
#define NTYPES    6
#define M_EDGES   400000
#define TOTAL_E   2400000
#define HALF_E    1200000
#define QUART_E   600000
#define NCNT      200000   // 2 halves * N_NODES
#define NCOPY     8
#define NSCAN     1600000  // NCOPY * NCNT, copy-major: lin = c*NCNT + slot
#define SCAN_BLKS 1563     // ceil(NSCAN/1024)

typedef _Float16 f16x8 __attribute__((ext_vector_type(8)));
typedef _Float16 f16x4 __attribute__((ext_vector_type(4)));
typedef float    f32x4 __attribute__((ext_vector_type(4)));

// ---- A16 = fp16(X), rows padded to M_PAD ----------------------------------
__global__ void build_a16(const float* __restrict__ x, _Float16* __restrict__ Ap){
    int tid = blockIdx.x * 256 + threadIdx.x;   // M_PAD*256/8 threads exact
    int idx = tid << 3;
    int row = idx >> 8;
    int k   = idx & 255;
    f16x8 h;
    if (row < N_NODES){
        const f32x4* px = (const f32x4*)(x + (size_t)row * DIM + k);
        f32x4 v0 = __builtin_nontemporal_load(px);
        f32x4 v1 = __builtin_nontemporal_load(px + 1);
        h[0] = (_Float16)v0[0]; h[1] = (_Float16)v0[1]; h[2] = (_Float16)v0[2]; h[3] = (_Float16)v0[3];
        h[4] = (_Float16)v1[0]; h[5] = (_Float16)v1[1]; h[6] = (_Float16)v1[2]; h[7] = (_Float16)v1[3];
    } else {
        #pragma unroll
        for (int j = 0; j < 8; ++j) h[j] = (_Float16)0.f;
    }
    *(f16x8*)(Ap + (size_t)row * 256 + k) = h;
}

// ---- B16 = fp16(W)  (1536 x 256) ------------------------------------------
__global__ void build_b16(const float* __restrict__ W, _Float16* __restrict__ Bp){
    int tid = blockIdx.x * 256 + threadIdx.x;   // 1536*256/8 threads exact
    int idx = tid << 3;
    const f32x4* pw = (const f32x4*)(W + idx);
    f32x4 v0 = __builtin_nontemporal_load(pw);
    f32x4 v1 = __builtin_nontemporal_load(pw + 1);
    f16x8 h;
    h[0] = (_Float16)v0[0]; h[1] = (_Float16)v0[1]; h[2] = (_Float16)v0[2]; h[3] = (_Float16)v0[3];
    h[4] = (_Float16)v1[0]; h[5] = (_Float16)v1[1]; h[6] = (_Float16)v1[2]; h[7] = (_Float16)v1[3];
    *(f16x8*)(Bp + idx) = h;
}

// ---- gating table 2*sigmoid(posemb @ Wp^T + bp), fp64 trig, fp16 out ------
__global__ void build_gating(const float* __restrict__ Wp, const float* __restrict__ bp,
                             _Float16* __restrict__ gate){
    __shared__ float semb[256];
    int p = blockIdx.x;     // 0..511
    int t = threadIdx.x;    // 0..255
    if (t < 127){
        double invf = exp(-log(10000.0) * (2.0 * t) / 254.0);
        double a = (double)p * invf;
        semb[t]       = (float)sin(a);
        semb[t + 127] = (float)cos(a);
    } else if (t >= 254){
        semb[t] = 0.0f;
    }
    __syncthreads();
    float z = bp[t];
    const float* wr = Wp + (size_t)t * 256;
    #pragma unroll 4
    for (int kq = 0; kq < 256; ++kq) z += semb[kq] * wr[kq];
    gate[(size_t)p * 256 + t] = (_Float16)(2.0f / (1.0f + expf(-z)));
}

// ---- CSR over (half,tgt), copy-major: each XCD owns a private contiguous --
// region of packed[]  (cnt/cursor/off_lin all at lin = copy*NCNT + slot)
__global__ void hist_kernel(const int* __restrict__ edges, int* __restrict__ cnt){
    int t0 = blockIdx.x * 256 + threadIdx.x;
    if (t0 >= QUART_E) return;
    int copy = blockIdx.x & 7;
    #pragma unroll
    for (int j = 0; j < 4; ++j){
        int e = t0 + j * QUART_E;
        int half = e / HALF_E;
        int tgt = edges[(size_t)e * 2 + 1];
        atomicAdd(cnt + copy * NCNT + half * N_NODES + tgt, 1);
    }
}

__global__ void scan1_kernel(const int* __restrict__ cnt, int* __restrict__ off_lin,
                             int* __restrict__ bsum){
    __shared__ int lds[256];
    int t = threadIdx.x;
    int base = blockIdx.x * 1024 + t * 4;
    int v[4]; int s = 0;
    #pragma unroll
    for (int j = 0; j < 4; ++j){
        int i = base + j;
        int val = (i < NSCAN) ? cnt[i] : 0;
        v[j] = val; s += val;
    }
    lds[t] = s; __syncthreads();
    for (int d = 1; d < 256; d <<= 1){
        int xv = (t >= d) ? lds[t - d] : 0;
        __syncthreads();
        lds[t] += xv;
        __syncthreads();
    }
    int run = (t > 0) ? lds[t - 1] : 0;
    #pragma unroll
    for (int j = 0; j < 4; ++j){ int i = base + j; if (i < NSCAN) off_lin[i] = run; run += v[j]; }
    if (t == 255) bsum[blockIdx.x] = run;
}

__global__ void scan2_kernel(const int* __restrict__ bsum, int* __restrict__ ssum){
    __shared__ int lds[256];
    __shared__ int carry;
    int t = threadIdx.x;
    if (t == 0) carry = 0;
    __syncthreads();
    for (int ch = 0; ch < 7; ++ch){
        int idx = ch * 256 + t;
        int v = (idx < SCAN_BLKS) ? bsum[idx] : 0;
        lds[t] = v; __syncthreads();
        for (int d = 1; d < 256; d <<= 1){
            int xv = (t >= d) ? lds[t - d] : 0;
            __syncthreads();
            lds[t] += xv;
            __syncthreads();
        }
        int ex = carry + ((t > 0) ? lds[t - 1] : 0);
        if (idx < SCAN_BLKS) ssum[idx] = ex;
        __syncthreads();
        if (t == 255) carry += lds[255];
        __syncthreads();
    }
}

__global__ void scan3_kernel(int* __restrict__ off_lin, const int* __restrict__ ssum,
                             int* __restrict__ cursor){
    int i = blockIdx.x * 256 + threadIdx.x;   // NSCAN exact
    int vv = off_lin[i] + ssum[i >> 10];
    off_lin[i] = vv;
    cursor[i] = vv;
    if (i == 0) off_lin[NSCAN] = TOTAL_E;     // sentinel
}

__global__ void scatter_kernel(const int* __restrict__ edges, const int* __restrict__ posl,
                               int* __restrict__ cursor, unsigned* __restrict__ packed){
    int t0 = blockIdx.x * 256 + threadIdx.x;
    if (t0 >= QUART_E) return;
    int copy = blockIdx.x & 7;
    #pragma unroll
    for (int j = 0; j < 4; ++j){
        int e = t0 + j * QUART_E;
        int type = e / M_EDGES;
        int half = e / HALF_E;
        int typ3 = type - half * 3;
        int2 ed = *(const int2*)(edges + (size_t)e * 2);
        int p = atomicAdd(cursor + copy * NCNT + half * N_NODES + ed.y, 1);
        packed[p] = (unsigned)ed.x | ((unsigned)posl[e] << 17) | ((unsigned)typ3 << 26);
    }
}

// ---- fp16 NT GEMM trio: prop_t = A16 * B_t^T + b_t for 3 types ------------
// staging: global_load_lds width-16, pre-swizzled global source, linear LDS
// dest (chunkbase + lane*16). LDS image identical to prior reg-staged version.
__global__ __launch_bounds__(512, 4) void gemm_f16(
        const _Float16* __restrict__ Ap,
        const _Float16* __restrict__ Bbase,
        const float* __restrict__ bbase,
        _Float16* __restrict__ prop)
{
    __shared__ __align__(16) char smem[49152];
    _Float16* sA = (_Float16*)smem;                 // 128*64 fp16 = 16 KB
    _Float16* sB = (_Float16*)(smem + 16384);       // 256*64 fp16 = 32 KB
    const int bid  = blockIdx.x;
    const int rp   = bid / 3;
    const int t    = bid - rp * 3;
    const int tid  = threadIdx.x;
    const int lane = tid & 63;
    const int wid  = tid >> 6;
    const int wr   = wid >> 2;   // 0..1
    const int wc   = wid & 3;    // 0..3
    const size_t m0 = (size_t)rp * 128;
    const _Float16* Bt = Bbase + (size_t)t * 256 * 256;

    f32x4 acc[4][4];
    #pragma unroll
    for (int m = 0; m < 4; ++m)
        #pragma unroll
        for (int n = 0; n < 4; ++n)
            acc[m][n] = (f32x4){0.f, 0.f, 0.f, 0.f};

    const int sub = lane >> 3;        // row within 8-row chunk (== r & 7)
    const int bib = (lane & 7) << 4;  // byte within 128B row
    const int soff = bib ^ (sub << 4);  // pre-swizzled source byte offset

    for (int kk = 0; kk < 4; ++kk){
        #pragma unroll
        for (int ci = 0; ci < 6; ++ci){
            int c = wid * 6 + ci;
            const char* gsrc;
            char* ldst;
            if (c < 16){
                gsrc = (const char*)(Ap + (m0 + (size_t)((c << 3) + sub)) * 256);
                ldst = (char*)smem + (c << 10);
            } else {
                int c2 = c - 16;
                gsrc = (const char*)(Bt + ((size_t)(c2 << 3) + sub) * 256);
                ldst = (char*)smem + 16384 + (c2 << 10);
            }
            __builtin_amdgcn_global_load_lds(
                (const __attribute__((address_space(1))) void*)(gsrc + (kk << 7) + soff),
                (__attribute__((address_space(3))) void*)ldst, 16, 0, 0);
        }
        __syncthreads();

        #pragma unroll
        for (int ks = 0; ks < 2; ++ks){
            int slot = (ks << 6) + ((lane >> 4) << 4);
            f16x8 af[4];
            #pragma unroll
            for (int m = 0; m < 4; ++m){
                int rA = (wr << 6) + (m << 4) + (lane & 15);
                af[m] = *(const f16x8*)((const char*)sA + rA * 128 + (slot ^ ((rA & 7) << 4)));
            }
            #pragma unroll
            for (int n = 0; n < 4; ++n){
                int rB = (wc << 6) + (n << 4) + (lane & 15);
                f16x8 bfr = *(const f16x8*)((const char*)sB + rB * 128 + (slot ^ ((rB & 7) << 4)));
                #pragma unroll
                for (int m = 0; m < 4; ++m)
                    acc[m][n] = __builtin_amdgcn_mfma_f32_16x16x32_f16(af[m], bfr, acc[m][n], 0, 0, 0);
            }
        }
        __syncthreads();
    }

    // ---- coalesced epilogue: stage 32-row half-tiles in private LDS slice --
    char* stage = smem + wid * 4096;
    _Float16* Ct = prop + (size_t)t * M_PAD * 256;
    float bv[4];
    #pragma unroll
    for (int n = 0; n < 4; ++n)
        bv[n] = bbase[(size_t)t * 256 + (wc << 6) + (n << 4) + (lane & 15)];

    #pragma unroll
    for (int ph = 0; ph < 2; ++ph){
        #pragma unroll
        for (int m2 = 0; m2 < 2; ++m2){
            int m = (ph << 1) + m2;
            #pragma unroll
            for (int n = 0; n < 4; ++n){
                #pragma unroll
                for (int j = 0; j < 4; ++j){
                    int lrow  = (m2 << 4) + ((lane >> 4) << 2) + j;
                    int lcolb = ((((n << 4) + (lane & 15)) << 1)) ^ (((lrow >> 2) & 3) << 5);
                    *(_Float16*)(stage + lrow * 128 + lcolb) =
                        (_Float16)(acc[m][n][j] + bv[n]);
                }
            }
        }
        #pragma unroll
        for (int r8 = 0; r8 < 4; ++r8){
            int lrow  = (r8 << 3) + (lane >> 3);
            int lcolb = (((lane & 7) << 4)) ^ (((lrow >> 2) & 3) << 5);
            f16x8 v = *(const f16x8*)(stage + lrow * 128 + lcolb);
            int grow = (int)m0 + (wr << 6) + (ph << 5) + lrow;
            int gcol = (wc << 6) + ((lane & 7) << 3);
            *(f16x8*)(Ct + (size_t)grow * 256 + gcol) = v;
        }
    }
}

// ---- half aggregation: 3 L3-resident props, one wave per target ------------
// (round-6 version: ILP-2, plain loads)  h==0: store. h==1: RMW + divide.
__global__ void aggregate(const _Float16* __restrict__ prop, const _Float16* __restrict__ gate,
                          const unsigned* __restrict__ packed,
                          const int* __restrict__ off_lin,
                          int h, float* __restrict__ out)
{
    int tgt  = blockIdx.x * 4 + (threadIdx.x >> 6);
    int lane = threadIdx.x & 63;
    int s    = h * N_NODES + tgt;

    int st[8], P[9];
    P[0] = 0;
    #pragma unroll
    for (int c = 0; c < 8; ++c){
        int a0 = off_lin[c * NCNT + s];
        int a1 = off_lin[c * NCNT + s + 1];
        st[c] = a0;
        P[c + 1] = P[c] + (a1 - a0);
    }
    int n = P[8];

    float4 a0v = make_float4(0.f, 0.f, 0.f, 0.f);
    float4 a1v = make_float4(0.f, 0.f, 0.f, 0.f);
    for (int c0 = 0; c0 < n; c0 += 64){
        int e = c0 + lane;
        int idx = st[0] + e;
        #pragma unroll
        for (int c = 1; c < 8; ++c)
            if (e >= P[c]) idx = st[c] + (e - P[c]);
        unsigned wv = (e < n) ? packed[idx] : 0u;
        int m = n - c0; if (m > 64) m = 64;
        int e2 = 0;
        for (; e2 + 1 < m; e2 += 2){
            unsigned w0 = (unsigned)__builtin_amdgcn_readlane((int)wv, e2);
            unsigned w1 = (unsigned)__builtin_amdgcn_readlane((int)wv, e2 + 1);
            int src0  = (int)(w0 & 0x1FFFFu);
            int pz0   = (int)((w0 >> 17) & 0x1FFu);
            int ty0   = (int)(w0 >> 26);
            int src1  = (int)(w1 & 0x1FFFFu);
            int pz1   = (int)((w1 >> 17) & 0x1FFu);
            int ty1   = (int)(w1 >> 26);
            f16x4 pv0 = *(const f16x4*)(prop + ((size_t)ty0 * M_PAD + (size_t)src0) * 256 + lane * 4);
            f16x4 gv0 = *(const f16x4*)(gate + (size_t)pz0 * 256 + lane * 4);
            f16x4 pv1 = *(const f16x4*)(prop + ((size_t)ty1 * M_PAD + (size_t)src1) * 256 + lane * 4);
            f16x4 gv1 = *(const f16x4*)(gate + (size_t)pz1 * 256 + lane * 4);
            a0v.x += (float)pv0[0] * (float)gv0[0];
            a0v.y += (float)pv0[1] * (float)gv0[1];
            a0v.z += (float)pv0[2] * (float)gv0[2];
            a0v.w += (float)pv0[3] * (float)gv0[3];
            a1v.x += (float)pv1[0] * (float)gv1[0];
            a1v.y += (float)pv1[1] * (float)gv1[1];
            a1v.z += (float)pv1[2] * (float)gv1[2];
            a1v.w += (float)pv1[3] * (float)gv1[3];
        }
        if (e2 < m){
            unsigned w0 = (unsigned)__builtin_amdgcn_readlane((int)wv, e2);
            int src0  = (int)(w0 & 0x1FFFFu);
            int pz0   = (int)((w0 >> 17) & 0x1FFu);
            int ty0   = (int)(w0 >> 26);
            f16x4 pv0 = *(const f16x4*)(prop + ((size_t)ty0 * M_PAD + (size_t)src0) * 256 + lane * 4);
            f16x4 gv0 = *(const f16x4*)(gate + (size_t)pz0 * 256 + lane * 4);
            a0v.x += (float)pv0[0] * (float)gv0[0];
            a0v.y += (float)pv0[1] * (float)gv0[1];
            a0v.z += (float)pv0[2] * (float)gv0[2];
            a0v.w += (float)pv0[3] * (float)gv0[3];
        }
    }
    a0v.x += a1v.x; a0v.y += a1v.y; a0v.z += a1v.z; a0v.w += a1v.w;
    float4* op = (float4*)(out + (size_t)tgt * DIM) + lane;
    if (h == 0){
        *op = a0v;
    } else {
        int deg = n;
        #pragma unroll
        for (int c = 0; c < 8; ++c)
            deg += off_lin[c * NCNT + tgt + 1] - off_lin[c * NCNT + tgt];
        float inv = ((deg == 0) ? 1.0f : (float)deg) + 1e-8f;
        float4 cc = *op;
        cc.x = (cc.x + a0v.x) / inv;
        cc.y = (cc.y + a0v.y) / inv;
        cc.z = (cc.z + a0v.z) / inv;
        cc.w = (cc.w + a0v.w) / inv;
        *op = cc;
    }
}

extern "C" void kernel_launch(void* const* d_in, const int* in_sizes, int n_in,
                              void* d_out, int out_size, void* d_ws, size_t ws_size,
                              hipStream_t stream)
{
    const float* x     = (const float*)d_in[0];
    const float* W     = (const float*)d_in[1];
    const float* b     = (const float*)d_in[2];
    const float* Wp    = (const float*)d_in[3];
    const float* bp    = (const float*)d_in[4];
    const int*   edges = (const int*)d_in[5];
    const int*   posl  = (const int*)d_in[6];
    float* out = (float*)d_out;

    char* ws = (char*)d_ws;
    size_t o = 0;
    auto alloc = [&](size_t bytes){ void* p = ws + o; o += (bytes + 255) & ~(size_t)255; return p; };

    _Float16* Ap   = (_Float16*)alloc((size_t)M_PAD * 256 * 2);
    _Float16* prop = (_Float16*)alloc((size_t)3 * M_PAD * 256 * 2);
    _Float16* Bp   = (_Float16*)alloc((size_t)NTYPES * 256 * 256 * 2);
    _Float16* gate = (_Float16*)alloc((size_t)512 * 256 * 2);
    int* cnt     = (int*)alloc((size_t)NSCAN * 4);
    int* off_lin = (int*)alloc((size_t)(NSCAN + 8) * 4);
    int* cursor  = (int*)alloc((size_t)NSCAN * 4);
    unsigned* packed = (unsigned*)alloc((size_t)TOTAL_E * 4);
    int* bsum   = (int*)alloc((size_t)SCAN_BLKS * 4 + 256);
    int* ssum   = (int*)alloc((size_t)SCAN_BLKS * 4 + 256);

    hipMemsetAsync(cnt, 0, (size_t)NSCAN * 4, stream);

    build_a16<<<12512, 256, 0, stream>>>(x, Ap);
    build_b16<<<192, 256, 0, stream>>>(W, Bp);
    build_gating<<<512, 256, 0, stream>>>(Wp, bp, gate);
    hist_kernel<<<2344, 256, 0, stream>>>(edges, cnt);
    scan1_kernel<<<SCAN_BLKS, 256, 0, stream>>>(cnt, off_lin, bsum);
    scan2_kernel<<<1, 256, 0, stream>>>(bsum, ssum);
    scan3_kernel<<<6250, 256, 0, stream>>>(off_lin, ssum, cursor);
    scatter_kernel<<<2344, 256, 0, stream>>>(edges, posl, cursor, packed);

    for (int h = 0; h < 2; ++h){
        gemm_f16<<<2346, 512, 0, stream>>>(Ap, Bp + (size_t)h * 3 * 256 * 256,
                                           b + (size_t)h * 3 * 256, prop);
        aggregate<<<25000, 256, 0, stream>>>(prop, gate, packed, off_lin, h, out);
    }
}